// Round 7
// baseline (585.312 us; speedup 1.0000x reference)
//
#include <hip/hip_runtime.h>

// Problem constants
constexpr int NB = 4, NS = 1024, NE = 1024, NH = 16, NFF = 4096;
constexpr int NM = NB * NS; // 4096 token rows

typedef short s8v __attribute__((ext_vector_type(8)));
typedef short s4v __attribute__((ext_vector_type(4)));
typedef float f4  __attribute__((ext_vector_type(4)));

__device__ __forceinline__ float b2f(unsigned short u) {
    union { unsigned int i; float f; } v; v.i = ((unsigned int)u) << 16; return v.f;
}
__device__ __forceinline__ unsigned short f2b(float f) {
    union { float f; unsigned int i; } v; v.f = f;
    unsigned int r = v.i + 0x7FFFu + ((v.i >> 16) & 1u);
    return (unsigned short)(r >> 16);
}
__device__ __forceinline__ float sigf(float x) { return 1.f / (1.f + __expf(-x)); }

#define GL2LDS(g, l) __builtin_amdgcn_global_load_lds( \
    (const __attribute__((address_space(1))) void*)(g), \
    (__attribute__((address_space(3))) void*)(l), 16, 0, 0)

// ---------------------------------------------------------------------------
// fp32 -> bf16 elementwise (x)
__global__ __launch_bounds__(256) void cvt_x_kernel(
    const float* __restrict__ X, unsigned short* __restrict__ O)
{
    size_t i = ((size_t)blockIdx.x * 256 + threadIdx.x) * 8;
    f4 v0 = *(const f4*)(X + i), v1 = *(const f4*)(X + i + 4);
    s8v o;
#pragma unroll
    for (int j = 0; j < 4; j++) { o[j] = (short)f2b(v0[j]); o[4 + j] = (short)f2b(v1[j]); }
    *(s8v*)(O + i) = o;
}

// ---------------------------------------------------------------------------
// fp32 W[K][N] -> bf16 WT[N][K] (transpose + convert), 64x64 tiles.
// blockIdx.z selects among up to 5 (src,dst) pairs (launch-count fusion).
__global__ __launch_bounds__(256) void cvt_t_kernel(
    const float* s0, const float* s1, const float* s2, const float* s3, const float* s4,
    unsigned short* d0, unsigned short* d1, unsigned short* d2, unsigned short* d3,
    unsigned short* d4, int K, int N)
{
    const int z = blockIdx.z;
    const float* W = (z == 0) ? s0 : (z == 1) ? s1 : (z == 2) ? s2 : (z == 3) ? s3 : s4;
    unsigned short* WT = (z == 0) ? d0 : (z == 1) ? d1 : (z == 2) ? d2 : (z == 3) ? d3 : d4;
    __shared__ unsigned short L[64][72];
    const int k0 = blockIdx.y * 64, n0 = blockIdx.x * 64;
    const int t = threadIdx.x;
    const int r = t >> 4, c4 = (t & 15) * 4;
#pragma unroll
    for (int p = 0; p < 4; p++) {
        int k = r + p * 16;
        f4 v = *(const f4*)&W[(size_t)(k0 + k) * N + n0 + c4];
#pragma unroll
        for (int i = 0; i < 4; i++) L[c4 + i][k] = f2b(v[i]);
    }
    __syncthreads();
    const int n = t >> 2, kc = (t & 3) * 16;
    s8v o0, o1;
#pragma unroll
    for (int i = 0; i < 8; i++) { o0[i] = (short)L[n][kc + i]; o1[i] = (short)L[n][kc + 8 + i]; }
    unsigned short* dst = WT + (size_t)(n0 + n) * K + k0 + kc;
    *(s8v*)dst = o0; *(s8v*)(dst + 8) = o1;
}

// ---------------------------------------------------------------------------
// pos_bias: biasL[q][k] = (mean8(pe) - 8) * log2(e)   [fixed-shift softmax fold]
__global__ __launch_bounds__(256) void posmean_kernel(
    const float* __restrict__ pe, float* __restrict__ bias)
{
    int idx = blockIdx.x * 256 + threadIdx.x;
    const float* p = pe + (size_t)idx * 8;
    f4 v0 = *(const f4*)p, v1 = *(const f4*)(p + 4);
    float s = 0.f;
#pragma unroll
    for (int i = 0; i < 4; i++) s += v0[i] + v1[i];
    bias[idx] = (s * 0.125f - 8.0f) * 1.44269504f;
}

// ---------------------------------------------------------------------------
// MFMA GEMM, BT layout, global_load_lds staging (m97 structure) with
// XOR bank-swizzle: logical 16B-chunk c of row r lives at physical c^((r>>2)&3).
// C[M,N] = epi(A[M,K] @ BT[N,K]^T + bias). Tile (32*TM)x128, BK=32, 4 waves.
#define EPI_QKVG     0  // bias per 1024-seg; sigmoid if gn>=3072
#define EPI_GATE_RES 2  // C = ex1 + ex2 * v   (ex2 row stride 4096, pre-offset)
#define EPI_RES      4  // C = ex1 + v
#define EPI_BIAS     5  // C = v

template <int EPI, int TM>
__global__ __launch_bounds__(256) void gemm_bt(
    const unsigned short* __restrict__ A,   // [M][K] bf16
    const unsigned short* __restrict__ BT,  // [N][K] bf16
    const float* b0p, const float* b1p, const float* b2p, const float* b3p,
    const unsigned short* ex1,              // row stride N (may alias C)
    const unsigned short* ex2,              // row stride 4096 (pre-offset)
    unsigned short* C, int M, int N, int K)
{
    constexpr int AR = 32 * TM; // A-tile rows
    __shared__ short As[AR * 32];
    __shared__ short Bs[128 * 32];

    const int tid  = threadIdx.x;
    const int m0   = blockIdx.y * AR;
    const int n0   = blockIdx.x * 128;
    const int lane = tid & 63;
    const int wave = tid >> 6;
    const int wm   = (wave >> 1) * (16 * TM), wn = (wave & 1) * 64;
    const int quad = lane >> 4, lo = lane & 15;
    const int lrow = lane >> 2;
    const int lcol = (((lane & 3) ^ ((lane >> 4) & 3))) * 8;
    const int rcol = ((quad ^ ((lo >> 2) & 3))) * 8;

    f4 acc[TM][4];
#pragma unroll
    for (int i = 0; i < TM; i++)
#pragma unroll
        for (int j = 0; j < 4; j++)
#pragma unroll
            for (int r = 0; r < 4; r++) acc[i][j][r] = 0.f;

    const unsigned short* ga = A  + (size_t)(m0 + wave * (AR / 4) + lrow) * K + lcol;
    const unsigned short* gb = BT + (size_t)(n0 + wave * 32 + lrow) * K + lcol;
    short* lA  = &As[(wave * (AR / 4)) * 32];
    short* lB0 = &Bs[(wave * 32) * 32];
    short* lB1 = &Bs[(wave * 32 + 16) * 32];

    for (int k0 = 0; k0 < K; k0 += 32) {
#pragma unroll
        for (int t = 0; t < TM / 2; t++)
            GL2LDS(ga + k0 + (size_t)t * 16 * K, lA + t * 16 * 32);
        GL2LDS(gb + k0,          lB0);
        GL2LDS(gb + k0 + 16 * K, lB1);
        __syncthreads();

        s8v af[TM], bf[4];
#pragma unroll
        for (int i = 0; i < TM; i++)
            af[i] = *(const s8v*)&As[(wm + i * 16 + lo) * 32 + rcol];
#pragma unroll
        for (int j = 0; j < 4; j++)
            bf[j] = *(const s8v*)&Bs[(wn + j * 16 + lo) * 32 + rcol];
#pragma unroll
        for (int i = 0; i < TM; i++)
#pragma unroll
            for (int j = 0; j < 4; j++)
                acc[i][j] = __builtin_amdgcn_mfma_f32_16x16x32_bf16(af[i], bf[j], acc[i][j], 0, 0, 0);
        __syncthreads();
    }

    const float* bp = b0p;
    bool do_sig = false;
    if (EPI == EPI_QKVG) {
        int seg = n0 >> 10;
        bp = (seg == 0) ? b0p : (seg == 1) ? b1p : (seg == 2) ? b2p : b3p;
        do_sig = (n0 >= 3072);
    }

    // epilogue: D layout col = lane&15, row = quad*4 + reg
#pragma unroll
    for (int i = 0; i < TM; i++) {
#pragma unroll
        for (int j = 0; j < 4; j++) {
#pragma unroll
            for (int r = 0; r < 4; r++) {
                int gm = m0 + wm + i * 16 + quad * 4 + r;
                int gn = n0 + wn + j * 16 + lo;
                size_t idx = (size_t)gm * N + gn;
                float v = acc[i][j][r] + (EPI == EPI_QKVG ? bp[gn & 1023] : bp[gn]);
                if (EPI == EPI_QKVG)          { if (do_sig) v = sigf(v); }
                else if (EPI == EPI_GATE_RES) v = b2f(ex1[idx]) + b2f(ex2[(size_t)gm * 4096 + gn]) * v;
                else if (EPI == EPI_RES)      v = b2f(ex1[idx]) + v;
                C[idx] = f2b(v);
            }
        }
    }
}

// ---------------------------------------------------------------------------
// Fused FF GEMM: C = (A@B1^T + bias1) * sigmoid(A@B2^T + bias2).
// A-tile staged once, both B-tiles staged, 32 MFMA per wave-iter (2x density).
template <int TM>
__global__ __launch_bounds__(256) void gemm_ff(
    const unsigned short* __restrict__ A,
    const unsigned short* __restrict__ B1T,
    const unsigned short* __restrict__ B2T,
    const float* __restrict__ bias1, const float* __restrict__ bias2,
    unsigned short* __restrict__ C, int M, int N, int K)
{
    constexpr int AR = 32 * TM;
    __shared__ short As[AR * 32];
    __shared__ short B1s[128 * 32];
    __shared__ short B2s[128 * 32];

    const int tid  = threadIdx.x;
    const int m0   = blockIdx.y * AR;
    const int n0   = blockIdx.x * 128;
    const int lane = tid & 63;
    const int wave = tid >> 6;
    const int wm   = (wave >> 1) * (16 * TM), wn = (wave & 1) * 64;
    const int quad = lane >> 4, lo = lane & 15;
    const int lrow = lane >> 2;
    const int lcol = (((lane & 3) ^ ((lane >> 4) & 3))) * 8;
    const int rcol = ((quad ^ ((lo >> 2) & 3))) * 8;

    f4 accA[TM][4], accB[TM][4];
#pragma unroll
    for (int i = 0; i < TM; i++)
#pragma unroll
        for (int j = 0; j < 4; j++)
#pragma unroll
            for (int r = 0; r < 4; r++) { accA[i][j][r] = 0.f; accB[i][j][r] = 0.f; }

    const unsigned short* ga  = A   + (size_t)(m0 + wave * (AR / 4) + lrow) * K + lcol;
    const unsigned short* gb1 = B1T + (size_t)(n0 + wave * 32 + lrow) * K + lcol;
    const unsigned short* gb2 = B2T + (size_t)(n0 + wave * 32 + lrow) * K + lcol;
    short* lA   = &As[(wave * (AR / 4)) * 32];
    short* lB10 = &B1s[(wave * 32) * 32];
    short* lB11 = &B1s[(wave * 32 + 16) * 32];
    short* lB20 = &B2s[(wave * 32) * 32];
    short* lB21 = &B2s[(wave * 32 + 16) * 32];

    for (int k0 = 0; k0 < K; k0 += 32) {
#pragma unroll
        for (int t = 0; t < TM / 2; t++)
            GL2LDS(ga + k0 + (size_t)t * 16 * K, lA + t * 16 * 32);
        GL2LDS(gb1 + k0,          lB10);
        GL2LDS(gb1 + k0 + 16 * K, lB11);
        GL2LDS(gb2 + k0,          lB20);
        GL2LDS(gb2 + k0 + 16 * K, lB21);
        __syncthreads();

        s8v af[TM], b1f[4], b2f_[4];
#pragma unroll
        for (int i = 0; i < TM; i++)
            af[i] = *(const s8v*)&As[(wm + i * 16 + lo) * 32 + rcol];
#pragma unroll
        for (int j = 0; j < 4; j++) {
            b1f[j]  = *(const s8v*)&B1s[(wn + j * 16 + lo) * 32 + rcol];
            b2f_[j] = *(const s8v*)&B2s[(wn + j * 16 + lo) * 32 + rcol];
        }
#pragma unroll
        for (int i = 0; i < TM; i++)
#pragma unroll
            for (int j = 0; j < 4; j++) {
                accA[i][j] = __builtin_amdgcn_mfma_f32_16x16x32_bf16(af[i], b1f[j],  accA[i][j], 0, 0, 0);
                accB[i][j] = __builtin_amdgcn_mfma_f32_16x16x32_bf16(af[i], b2f_[j], accB[i][j], 0, 0, 0);
            }
        __syncthreads();
    }

#pragma unroll
    for (int i = 0; i < TM; i++) {
#pragma unroll
        for (int j = 0; j < 4; j++) {
#pragma unroll
            for (int r = 0; r < 4; r++) {
                int gm = m0 + wm + i * 16 + quad * 4 + r;
                int gn = n0 + wn + j * 16 + lo;
                float a = accA[i][j][r] + bias1[gn];
                float g = accB[i][j][r] + bias2[gn];
                C[(size_t)gm * N + gn] = f2b(a * sigf(g));
            }
        }
    }
}

// ---------------------------------------------------------------------------
// Flash attention, fixed-shift softmax (shift=8 folded into biasL, log2 domain).
__global__ __launch_bounds__(256) void attn_kernel(
    const unsigned short* __restrict__ QKVG, const float* __restrict__ bias,
    unsigned short* __restrict__ ctx)
{
    __shared__ short Ks[32 * 72];     // [kv][d]
    __shared__ short Vt[64 * 48];     // [d][perm kv]
    __shared__ short Ps[4][16 * 40];  // per-wave P [q][perm kv]

    const int tid = threadIdx.x;
    const int lane = tid & 63, wave = tid >> 6;
    const int quad = lane >> 4, lo = lane & 15;
    const int bh = blockIdx.y;
    const int b = bh >> 4, h = bh & 15;
    const int q0 = blockIdx.x * 64 + wave * 16;
    const size_t base  = (size_t)b * NS * 4096 + (size_t)h * 64;
    const size_t baseK = base + 1024, baseV = base + 2048;
    constexpr float c1 = 0.125f * 1.44269504f;

    s8v aq0 = *(const s8v*)(QKVG + base + (size_t)(q0 + lo) * 4096 + quad * 8);
    s8v aq1 = *(const s8v*)(QKVG + base + (size_t)(q0 + lo) * 4096 + 32 + quad * 8);

    f4 accO[4];
    float l_r[4];
#pragma unroll
    for (int r = 0; r < 4; r++) {
        l_r[r] = 0.f;
#pragma unroll
        for (int j = 0; j < 4; j++) accO[j][r] = 0.f;
    }

    const int skv = tid >> 3, sd8 = (tid & 7) * 8;
    const int vkv = tid & 31, vd8 = (tid >> 5) * 8;
    const int pvk = 2 * (vkv & 15) + (vkv >> 4);

    s8v kk = *(const s8v*)(QKVG + baseK + (size_t)skv * 4096 + sd8);
    s8v vv = *(const s8v*)(QKVG + baseV + (size_t)vkv * 4096 + vd8);

    for (int kv0 = 0; kv0 < NS; kv0 += 32) {
        *(s8v*)&Ks[skv * 72 + sd8] = kk;
#pragma unroll
        for (int i = 0; i < 8; i++) Vt[(vd8 + i) * 48 + pvk] = (short)vv[i];
        __syncthreads();

        s8v kkn = kk, vvn = vv;
        if (kv0 + 32 < NS) {
            kkn = *(const s8v*)(QKVG + baseK + (size_t)(kv0 + 32 + skv) * 4096 + sd8);
            vvn = *(const s8v*)(QKVG + baseV + (size_t)(kv0 + 32 + vkv) * 4096 + vd8);
        }

        f4 sc[2];
#pragma unroll
        for (int cb = 0; cb < 2; cb++) {
            s8v bk0 = *(const s8v*)&Ks[(cb * 16 + lo) * 72 + quad * 8];
            s8v bk1 = *(const s8v*)&Ks[(cb * 16 + lo) * 72 + 32 + quad * 8];
            f4 z;
#pragma unroll
            for (int r = 0; r < 4; r++) z[r] = 0.f;
            z = __builtin_amdgcn_mfma_f32_16x16x32_bf16(aq0, bk0, z, 0, 0, 0);
            sc[cb] = __builtin_amdgcn_mfma_f32_16x16x32_bf16(aq1, bk1, z, 0, 0, 0);
        }

        int* PsI = (int*)&Ps[wave][0];
#pragma unroll
        for (int r = 0; r < 4; r++) {
            int qrow = q0 + quad * 4 + r;
            const float* bp = &bias[(size_t)qrow * NS + kv0];
            float p0 = exp2f(sc[0][r] * c1 + bp[lo]);
            float p1 = exp2f(sc[1][r] * c1 + bp[16 + lo]);
            l_r[r] += p0 + p1;
            unsigned int pk = (unsigned int)f2b(p0) | ((unsigned int)f2b(p1) << 16);
            PsI[(quad * 4 + r) * 20 + lo] = (int)pk;
        }
        s8v pf = *(const s8v*)&Ps[wave][lo * 40 + quad * 8];
#pragma unroll
        for (int j = 0; j < 4; j++) {
            s8v bv = *(const s8v*)&Vt[(j * 16 + lo) * 48 + quad * 8];
            accO[j] = __builtin_amdgcn_mfma_f32_16x16x32_bf16(pf, bv, accO[j], 0, 0, 0);
        }
        __syncthreads();
        kk = kkn; vv = vvn;
    }

#pragma unroll
    for (int r = 0; r < 4; r++) {
        float l = l_r[r];
#pragma unroll
        for (int d = 1; d < 16; d <<= 1) l += __shfl_xor(l, d, 64);
        l_r[r] = 1.f / l;
    }
#pragma unroll
    for (int j = 0; j < 4; j++)
#pragma unroll
        for (int r = 0; r < 4; r++) {
            int qrow = q0 + quad * 4 + r;
            ctx[((size_t)b * NS + qrow) * 1024 + h * 64 + j * 16 + lo] = f2b(accO[j][r] * l_r[r]);
        }
}

// ---------------------------------------------------------------------------
// LayerNorm over last dim (1024). X bf16; g/b fp32 inputs; out bf16 or fp32.
__global__ __launch_bounds__(256) void ln_kernel(
    const unsigned short* __restrict__ X, const float* __restrict__ g,
    const float* __restrict__ bb, void* __restrict__ out, int outF32)
{
    const int row = blockIdx.x;
    const unsigned short* xr = X + (size_t)row * NE;
    s4v xv = *(const s4v*)(xr + threadIdx.x * 4);
    float v[4], s = 0.f, ss = 0.f;
#pragma unroll
    for (int i = 0; i < 4; i++) {
        v[i] = b2f((unsigned short)xv[i]);
        s += v[i]; ss += v[i] * v[i];
    }
#pragma unroll
    for (int d = 1; d < 64; d <<= 1) { s += __shfl_xor(s, d, 64); ss += __shfl_xor(ss, d, 64); }
    __shared__ float red[8];
    int wave = threadIdx.x >> 6, lane = threadIdx.x & 63;
    if (lane == 0) { red[wave] = s; red[4 + wave] = ss; }
    __syncthreads();
    s  = red[0] + red[1] + red[2] + red[3];
    ss = red[4] + red[5] + red[6] + red[7];
    float mu = s * (1.f / NE);
    float var = ss * (1.f / NE) - mu * mu;
    float rstd = rsqrtf(fmaxf(var, 0.f) + 1e-6f);
#pragma unroll
    for (int i = 0; i < 4; i++) {
        int c = threadIdx.x * 4 + i;
        size_t idx = (size_t)row * NE + c;
        float o = (v[i] - mu) * rstd * g[c] + bb[c];
        if (outF32) ((float*)out)[idx] = o;
        else        ((unsigned short*)out)[idx] = f2b(o);
    }
}

// ---------------------------------------------------------------------------
// Workspace map (peak 78 MB):
//   [0,8)   xb -> T1 -> T2
//   [8,16)  WTqkvg -> Cx -> X1
//   [16,18) WoT   [18,26) Wf1T   [26,34) WfgT   [34,42) Wf2T
//   [42,46) biasP (fp32, log2-domain, shift folded)
//   [46,78) QKVG -> H1
extern "C" void kernel_launch(void* const* d_in, const int* in_sizes, int n_in,
                              void* d_out, int out_size, void* d_ws, size_t ws_size,
                              hipStream_t stream)
{
    const float* x    = (const float*)d_in[0];
    const float* pe   = (const float*)d_in[1];
    const float* Wq   = (const float*)d_in[2];
    const float* bq   = (const float*)d_in[3];
    const float* Wk   = (const float*)d_in[4];
    const float* bk   = (const float*)d_in[5];
    const float* Wv   = (const float*)d_in[6];
    const float* bv   = (const float*)d_in[7];
    const float* Wo   = (const float*)d_in[8];
    const float* bo   = (const float*)d_in[9];
    const float* Wg   = (const float*)d_in[10];
    const float* bg   = (const float*)d_in[11];
    const float* Wf1  = (const float*)d_in[12];
    const float* bf1  = (const float*)d_in[13];
    const float* Wfg  = (const float*)d_in[14];
    const float* bfg  = (const float*)d_in[15];
    const float* Wf2  = (const float*)d_in[16];
    const float* bf2  = (const float*)d_in[17];
    const float* ln1g = (const float*)d_in[18];
    const float* ln1b = (const float*)d_in[19];
    const float* ln2g = (const float*)d_in[20];
    const float* ln2b = (const float*)d_in[21];

    char* ws = (char*)d_ws;
    unsigned short* xb    = (unsigned short*)ws;                         // [0,8)
    unsigned short* WTq   = (unsigned short*)(ws + ( 8ull << 20));       // [8,16)
    unsigned short* WoT   = (unsigned short*)(ws + (16ull << 20));       // [16,18)
    unsigned short* Wf1T  = (unsigned short*)(ws + (18ull << 20));       // [18,26)
    unsigned short* WfgT  = (unsigned short*)(ws + (26ull << 20));       // [26,34)
    unsigned short* Wf2T  = (unsigned short*)(ws + (34ull << 20));       // [34,42)
    float*          biasP = (float*)(ws + (42ull << 20));                // [42,46)
    unsigned short* QKVG  = (unsigned short*)(ws + (46ull << 20));       // [46,78)
    unsigned short* T1 = xb;
    unsigned short* Cx = WTq;
    unsigned short* X1 = WTq;
    unsigned short* H1 = QKVG;
    unsigned short* T2 = xb;

    dim3 blk(256);
    cvt_x_kernel<<<dim3(NM * NE / (256 * 8)), blk, 0, stream>>>(x, xb);
    cvt_t_kernel<<<dim3(16, 16, 5), blk, 0, stream>>>(
        Wq, Wk, Wv, Wg, Wo,
        WTq + 0ull * 1024 * 1024, WTq + 1ull * 1024 * 1024,
        WTq + 2ull * 1024 * 1024, WTq + 3ull * 1024 * 1024, WoT, NE, NE);
    cvt_t_kernel<<<dim3(64, 16, 2), blk, 0, stream>>>(
        Wf1, Wfg, nullptr, nullptr, nullptr,
        Wf1T, WfgT, nullptr, nullptr, nullptr, NE, NFF);
    cvt_t_kernel<<<dim3(16, 64, 1), blk, 0, stream>>>(
        Wf2, nullptr, nullptr, nullptr, nullptr,
        Wf2T, nullptr, nullptr, nullptr, nullptr, NFF, NE);
    posmean_kernel<<<dim3(NS * NS / 256), blk, 0, stream>>>(pe, biasP);

    // fused QKVG: [4096 x 4096] = xb @ [Wq|Wk|Wv|Wg], sigmoid on G segment
    gemm_bt<EPI_QKVG, 4><<<dim3(32, 32), blk, 0, stream>>>(
        xb, WTq, bq, bk, bv, bg, nullptr, nullptr, QKVG, NM, 4096, NE);

    attn_kernel<<<dim3(NS / 64, NB * NH), blk, 0, stream>>>(QKVG, biasP, Cx);

    // T1 = xb + G * (Cx@Wo + bo)   (T1 aliases xb: same-idx read-then-write)
    gemm_bt<EPI_GATE_RES, 2><<<dim3(8, 64), blk, 0, stream>>>(
        Cx, WoT, bo, nullptr, nullptr, nullptr, xb, QKVG + 3072, T1, NM, NE, NE);
    ln_kernel<<<dim3(NM), blk, 0, stream>>>(T1, ln1g, ln1b, X1, 0);

    // fused FF: H1 = (X1@Wf1 + bf1) * sigmoid(X1@Wfg + bfg)
    gemm_ff<4><<<dim3(32, 32), blk, 0, stream>>>(
        X1, Wf1T, WfgT, bf1, bfg, H1, NM, NFF, NE);

    gemm_bt<EPI_RES, 2><<<dim3(8, 64), blk, 0, stream>>>(
        H1, Wf2T, bf2, nullptr, nullptr, nullptr, X1, nullptr, T2, NM, NE, NFF);
    ln_kernel<<<dim3(NM), blk, 0, stream>>>(T2, ln2g, ln2b, d_out, 1);
}

// Round 8
// 513.808 us; speedup vs baseline: 1.1392x; 1.1392x over previous
//
#include <hip/hip_runtime.h>

// Problem constants
constexpr int NB = 4, NS = 1024, NE = 1024, NH = 16, NFF = 4096;
constexpr int NM = NB * NS; // 4096 token rows

typedef short s8v __attribute__((ext_vector_type(8)));
typedef short s4v __attribute__((ext_vector_type(4)));
typedef float f4  __attribute__((ext_vector_type(4)));

__device__ __forceinline__ float b2f(unsigned short u) {
    union { unsigned int i; float f; } v; v.i = ((unsigned int)u) << 16; return v.f;
}
__device__ __forceinline__ unsigned short f2b(float f) {
    union { float f; unsigned int i; } v; v.f = f;
    unsigned int r = v.i + 0x7FFFu + ((v.i >> 16) & 1u);
    return (unsigned short)(r >> 16);
}
__device__ __forceinline__ float sigf(float x) { return 1.f / (1.f + __expf(-x)); }

#define GL2LDS(g, l) __builtin_amdgcn_global_load_lds( \
    (const __attribute__((address_space(1))) void*)(g), \
    (__attribute__((address_space(3))) void*)(l), 16, 0, 0)

// ---------------------------------------------------------------------------
// fp32 -> bf16 elementwise (x)
__global__ __launch_bounds__(256) void cvt_x_kernel(
    const float* __restrict__ X, unsigned short* __restrict__ O)
{
    size_t i = ((size_t)blockIdx.x * 256 + threadIdx.x) * 8;
    f4 v0 = *(const f4*)(X + i), v1 = *(const f4*)(X + i + 4);
    s8v o;
#pragma unroll
    for (int j = 0; j < 4; j++) { o[j] = (short)f2b(v0[j]); o[4 + j] = (short)f2b(v1[j]); }
    *(s8v*)(O + i) = o;
}

// ---------------------------------------------------------------------------
// fp32 W[K][N] -> bf16 WT[N][K] (transpose + convert), 64x64 tiles.
// blockIdx.z selects among up to 5 (src,dst) pairs (launch-count fusion).
__global__ __launch_bounds__(256) void cvt_t_kernel(
    const float* s0, const float* s1, const float* s2, const float* s3, const float* s4,
    unsigned short* d0, unsigned short* d1, unsigned short* d2, unsigned short* d3,
    unsigned short* d4, int K, int N)
{
    const int z = blockIdx.z;
    const float* W = (z == 0) ? s0 : (z == 1) ? s1 : (z == 2) ? s2 : (z == 3) ? s3 : s4;
    unsigned short* WT = (z == 0) ? d0 : (z == 1) ? d1 : (z == 2) ? d2 : (z == 3) ? d3 : d4;
    __shared__ unsigned short L[64][72];
    const int k0 = blockIdx.y * 64, n0 = blockIdx.x * 64;
    const int t = threadIdx.x;
    const int r = t >> 4, c4 = (t & 15) * 4;
#pragma unroll
    for (int p = 0; p < 4; p++) {
        int k = r + p * 16;
        f4 v = *(const f4*)&W[(size_t)(k0 + k) * N + n0 + c4];
#pragma unroll
        for (int i = 0; i < 4; i++) L[c4 + i][k] = f2b(v[i]);
    }
    __syncthreads();
    const int n = t >> 2, kc = (t & 3) * 16;
    s8v o0, o1;
#pragma unroll
    for (int i = 0; i < 8; i++) { o0[i] = (short)L[n][kc + i]; o1[i] = (short)L[n][kc + 8 + i]; }
    unsigned short* dst = WT + (size_t)(n0 + n) * K + k0 + kc;
    *(s8v*)dst = o0; *(s8v*)(dst + 8) = o1;
}

// ---------------------------------------------------------------------------
// pos_bias: biasL[q][k] = (mean8(pe) - 8) * log2(e)   [fixed-shift softmax fold]
__global__ __launch_bounds__(256) void posmean_kernel(
    const float* __restrict__ pe, float* __restrict__ bias)
{
    int idx = blockIdx.x * 256 + threadIdx.x;
    const float* p = pe + (size_t)idx * 8;
    f4 v0 = *(const f4*)p, v1 = *(const f4*)(p + 4);
    float s = 0.f;
#pragma unroll
    for (int i = 0; i < 4; i++) s += v0[i] + v1[i];
    bias[idx] = (s * 0.125f - 8.0f) * 1.44269504f;
}

// ---------------------------------------------------------------------------
// MFMA GEMM, BT layout, global_load_lds staging, XOR bank-swizzle, BK=64 via
// twin 32-col LDS buffers (per-buffer layout identical to the BK=32 version;
// halves the number of barrier/vmcnt-drain pairs per K-loop).
// C[M,N] = epi(A[M,K] @ BT[N,K]^T + bias). Tile (32*TM)x128, 4 waves.
#define EPI_QKVG     0  // bias per 1024-seg; sigmoid if gn>=3072
#define EPI_GATE_RES 2  // C = ex1 + ex2 * v   (ex2 row stride 4096, pre-offset)
#define EPI_RES      4  // C = ex1 + v
#define EPI_BIAS     5  // C = v

template <int EPI, int TM>
__global__ __launch_bounds__(256) void gemm_bt(
    const unsigned short* __restrict__ A,   // [M][K] bf16
    const unsigned short* __restrict__ BT,  // [N][K] bf16
    const float* b0p, const float* b1p, const float* b2p, const float* b3p,
    const unsigned short* ex1,              // row stride N (may alias C)
    const unsigned short* ex2,              // row stride 4096 (pre-offset)
    unsigned short* C, int M, int N, int K)
{
    constexpr int AR = 32 * TM; // A-tile rows
    __shared__ short As0[AR * 32], As1[AR * 32];
    __shared__ short Bs0[128 * 32], Bs1[128 * 32];

    const int tid  = threadIdx.x;
    const int m0   = blockIdx.y * AR;
    const int n0   = blockIdx.x * 128;
    const int lane = tid & 63;
    const int wave = tid >> 6;
    const int wm   = (wave >> 1) * (16 * TM), wn = (wave & 1) * 64;
    const int quad = lane >> 4, lo = lane & 15;
    const int lrow = lane >> 2;
    const int lcol = (((lane & 3) ^ ((lane >> 4) & 3))) * 8;
    const int rcol = ((quad ^ ((lo >> 2) & 3))) * 8;

    f4 acc[TM][4];
#pragma unroll
    for (int i = 0; i < TM; i++)
#pragma unroll
        for (int j = 0; j < 4; j++)
#pragma unroll
            for (int r = 0; r < 4; r++) acc[i][j][r] = 0.f;

    const unsigned short* ga = A  + (size_t)(m0 + wave * (AR / 4) + lrow) * K + lcol;
    const unsigned short* gb = BT + (size_t)(n0 + wave * 32 + lrow) * K + lcol;
    short* lA0  = &As0[(wave * (AR / 4)) * 32];
    short* lA1  = &As1[(wave * (AR / 4)) * 32];
    short* lB00 = &Bs0[(wave * 32) * 32];
    short* lB01 = &Bs0[(wave * 32 + 16) * 32];
    short* lB10 = &Bs1[(wave * 32) * 32];
    short* lB11 = &Bs1[(wave * 32 + 16) * 32];

    for (int k0 = 0; k0 < K; k0 += 64) {
#pragma unroll
        for (int t = 0; t < TM / 2; t++) {
            GL2LDS(ga + k0 +      (size_t)t * 16 * K, lA0 + t * 16 * 32);
            GL2LDS(ga + k0 + 32 + (size_t)t * 16 * K, lA1 + t * 16 * 32);
        }
        GL2LDS(gb + k0,               lB00);
        GL2LDS(gb + k0 + 16 * K,      lB01);
        GL2LDS(gb + k0 + 32,          lB10);
        GL2LDS(gb + k0 + 32 + 16 * K, lB11);
        __syncthreads();

        s8v af[TM], bf[4];
        // K-half 0
#pragma unroll
        for (int i = 0; i < TM; i++)
            af[i] = *(const s8v*)&As0[(wm + i * 16 + lo) * 32 + rcol];
#pragma unroll
        for (int j = 0; j < 4; j++)
            bf[j] = *(const s8v*)&Bs0[(wn + j * 16 + lo) * 32 + rcol];
#pragma unroll
        for (int i = 0; i < TM; i++)
#pragma unroll
            for (int j = 0; j < 4; j++)
                acc[i][j] = __builtin_amdgcn_mfma_f32_16x16x32_bf16(af[i], bf[j], acc[i][j], 0, 0, 0);
        // K-half 1
#pragma unroll
        for (int i = 0; i < TM; i++)
            af[i] = *(const s8v*)&As1[(wm + i * 16 + lo) * 32 + rcol];
#pragma unroll
        for (int j = 0; j < 4; j++)
            bf[j] = *(const s8v*)&Bs1[(wn + j * 16 + lo) * 32 + rcol];
#pragma unroll
        for (int i = 0; i < TM; i++)
#pragma unroll
            for (int j = 0; j < 4; j++)
                acc[i][j] = __builtin_amdgcn_mfma_f32_16x16x32_bf16(af[i], bf[j], acc[i][j], 0, 0, 0);
        __syncthreads();
    }

    const float* bp = b0p;
    bool do_sig = false;
    if (EPI == EPI_QKVG) {
        int seg = n0 >> 10;
        bp = (seg == 0) ? b0p : (seg == 1) ? b1p : (seg == 2) ? b2p : b3p;
        do_sig = (n0 >= 3072);
    }

    // epilogue: D layout col = lane&15, row = quad*4 + reg
#pragma unroll
    for (int i = 0; i < TM; i++) {
#pragma unroll
        for (int j = 0; j < 4; j++) {
#pragma unroll
            for (int r = 0; r < 4; r++) {
                int gm = m0 + wm + i * 16 + quad * 4 + r;
                int gn = n0 + wn + j * 16 + lo;
                size_t idx = (size_t)gm * N + gn;
                float v = acc[i][j][r] + (EPI == EPI_QKVG ? bp[gn & 1023] : bp[gn]);
                if (EPI == EPI_QKVG)          { if (do_sig) v = sigf(v); }
                else if (EPI == EPI_GATE_RES) v = b2f(ex1[idx]) + b2f(ex2[(size_t)gm * 4096 + gn]) * v;
                else if (EPI == EPI_RES)      v = b2f(ex1[idx]) + v;
                C[idx] = f2b(v);
            }
        }
    }
}

// ---------------------------------------------------------------------------
// Fused FF GEMM: C = (A@B1^T + bias1) * sigmoid(A@B2^T + bias2).
// TM=2 keeps dual accumulators within the register budget (R7 lesson:
// TM=4 -> 1 block/CU occupancy collapse). BK=32.
template <int TM>
__global__ __launch_bounds__(256) void gemm_ff(
    const unsigned short* __restrict__ A,
    const unsigned short* __restrict__ B1T,
    const unsigned short* __restrict__ B2T,
    const float* __restrict__ bias1, const float* __restrict__ bias2,
    unsigned short* __restrict__ C, int M, int N, int K)
{
    constexpr int AR = 32 * TM;
    __shared__ short As[AR * 32];
    __shared__ short B1s[128 * 32];
    __shared__ short B2s[128 * 32];

    const int tid  = threadIdx.x;
    const int m0   = blockIdx.y * AR;
    const int n0   = blockIdx.x * 128;
    const int lane = tid & 63;
    const int wave = tid >> 6;
    const int wm   = (wave >> 1) * (16 * TM), wn = (wave & 1) * 64;
    const int quad = lane >> 4, lo = lane & 15;
    const int lrow = lane >> 2;
    const int lcol = (((lane & 3) ^ ((lane >> 4) & 3))) * 8;
    const int rcol = ((quad ^ ((lo >> 2) & 3))) * 8;

    f4 accA[TM][4], accB[TM][4];
#pragma unroll
    for (int i = 0; i < TM; i++)
#pragma unroll
        for (int j = 0; j < 4; j++)
#pragma unroll
            for (int r = 0; r < 4; r++) { accA[i][j][r] = 0.f; accB[i][j][r] = 0.f; }

    const unsigned short* ga  = A   + (size_t)(m0 + wave * (AR / 4) + lrow) * K + lcol;
    const unsigned short* gb1 = B1T + (size_t)(n0 + wave * 32 + lrow) * K + lcol;
    const unsigned short* gb2 = B2T + (size_t)(n0 + wave * 32 + lrow) * K + lcol;
    short* lA   = &As[(wave * (AR / 4)) * 32];
    short* lB10 = &B1s[(wave * 32) * 32];
    short* lB11 = &B1s[(wave * 32 + 16) * 32];
    short* lB20 = &B2s[(wave * 32) * 32];
    short* lB21 = &B2s[(wave * 32 + 16) * 32];

    for (int k0 = 0; k0 < K; k0 += 32) {
#pragma unroll
        for (int t = 0; t < TM / 2; t++)
            GL2LDS(ga + k0 + (size_t)t * 16 * K, lA + t * 16 * 32);
        GL2LDS(gb1 + k0,          lB10);
        GL2LDS(gb1 + k0 + 16 * K, lB11);
        GL2LDS(gb2 + k0,          lB20);
        GL2LDS(gb2 + k0 + 16 * K, lB21);
        __syncthreads();

        s8v af[TM], b1f[4], b2f_[4];
#pragma unroll
        for (int i = 0; i < TM; i++)
            af[i] = *(const s8v*)&As[(wm + i * 16 + lo) * 32 + rcol];
#pragma unroll
        for (int j = 0; j < 4; j++) {
            b1f[j]  = *(const s8v*)&B1s[(wn + j * 16 + lo) * 32 + rcol];
            b2f_[j] = *(const s8v*)&B2s[(wn + j * 16 + lo) * 32 + rcol];
        }
#pragma unroll
        for (int i = 0; i < TM; i++)
#pragma unroll
            for (int j = 0; j < 4; j++) {
                accA[i][j] = __builtin_amdgcn_mfma_f32_16x16x32_bf16(af[i], b1f[j],  accA[i][j], 0, 0, 0);
                accB[i][j] = __builtin_amdgcn_mfma_f32_16x16x32_bf16(af[i], b2f_[j], accB[i][j], 0, 0, 0);
            }
        __syncthreads();
    }

#pragma unroll
    for (int i = 0; i < TM; i++) {
#pragma unroll
        for (int j = 0; j < 4; j++) {
#pragma unroll
            for (int r = 0; r < 4; r++) {
                int gm = m0 + wm + i * 16 + quad * 4 + r;
                int gn = n0 + wn + j * 16 + lo;
                float a = accA[i][j][r] + bias1[gn];
                float g = accB[i][j][r] + bias2[gn];
                C[(size_t)gm * N + gn] = f2b(a * sigf(g));
            }
        }
    }
}

// ---------------------------------------------------------------------------
// Flash attention, fixed-shift softmax (shift=8 folded into biasL, log2 domain).
__global__ __launch_bounds__(256) void attn_kernel(
    const unsigned short* __restrict__ QKVG, const float* __restrict__ bias,
    unsigned short* __restrict__ ctx)
{
    __shared__ short Ks[32 * 72];     // [kv][d]
    __shared__ short Vt[64 * 48];     // [d][perm kv]
    __shared__ short Ps[4][16 * 40];  // per-wave P [q][perm kv]

    const int tid = threadIdx.x;
    const int lane = tid & 63, wave = tid >> 6;
    const int quad = lane >> 4, lo = lane & 15;
    const int bh = blockIdx.y;
    const int b = bh >> 4, h = bh & 15;
    const int q0 = blockIdx.x * 64 + wave * 16;
    const size_t base  = (size_t)b * NS * 4096 + (size_t)h * 64;
    const size_t baseK = base + 1024, baseV = base + 2048;
    constexpr float c1 = 0.125f * 1.44269504f;

    s8v aq0 = *(const s8v*)(QKVG + base + (size_t)(q0 + lo) * 4096 + quad * 8);
    s8v aq1 = *(const s8v*)(QKVG + base + (size_t)(q0 + lo) * 4096 + 32 + quad * 8);

    f4 accO[4];
    float l_r[4];
#pragma unroll
    for (int r = 0; r < 4; r++) {
        l_r[r] = 0.f;
#pragma unroll
        for (int j = 0; j < 4; j++) accO[j][r] = 0.f;
    }

    const int skv = tid >> 3, sd8 = (tid & 7) * 8;
    const int vkv = tid & 31, vd8 = (tid >> 5) * 8;
    const int pvk = 2 * (vkv & 15) + (vkv >> 4);

    s8v kk = *(const s8v*)(QKVG + baseK + (size_t)skv * 4096 + sd8);
    s8v vv = *(const s8v*)(QKVG + baseV + (size_t)vkv * 4096 + vd8);

    for (int kv0 = 0; kv0 < NS; kv0 += 32) {
        *(s8v*)&Ks[skv * 72 + sd8] = kk;
#pragma unroll
        for (int i = 0; i < 8; i++) Vt[(vd8 + i) * 48 + pvk] = (short)vv[i];
        __syncthreads();

        s8v kkn = kk, vvn = vv;
        if (kv0 + 32 < NS) {
            kkn = *(const s8v*)(QKVG + baseK + (size_t)(kv0 + 32 + skv) * 4096 + sd8);
            vvn = *(const s8v*)(QKVG + baseV + (size_t)(kv0 + 32 + vkv) * 4096 + vd8);
        }

        f4 sc[2];
#pragma unroll
        for (int cb = 0; cb < 2; cb++) {
            s8v bk0 = *(const s8v*)&Ks[(cb * 16 + lo) * 72 + quad * 8];
            s8v bk1 = *(const s8v*)&Ks[(cb * 16 + lo) * 72 + 32 + quad * 8];
            f4 z;
#pragma unroll
            for (int r = 0; r < 4; r++) z[r] = 0.f;
            z = __builtin_amdgcn_mfma_f32_16x16x32_bf16(aq0, bk0, z, 0, 0, 0);
            sc[cb] = __builtin_amdgcn_mfma_f32_16x16x32_bf16(aq1, bk1, z, 0, 0, 0);
        }

        int* PsI = (int*)&Ps[wave][0];
#pragma unroll
        for (int r = 0; r < 4; r++) {
            int qrow = q0 + quad * 4 + r;
            const float* bp = &bias[(size_t)qrow * NS + kv0];
            float p0 = exp2f(sc[0][r] * c1 + bp[lo]);
            float p1 = exp2f(sc[1][r] * c1 + bp[16 + lo]);
            l_r[r] += p0 + p1;
            unsigned int pk = (unsigned int)f2b(p0) | ((unsigned int)f2b(p1) << 16);
            PsI[(quad * 4 + r) * 20 + lo] = (int)pk;
        }
        s8v pf = *(const s8v*)&Ps[wave][lo * 40 + quad * 8];
#pragma unroll
        for (int j = 0; j < 4; j++) {
            s8v bv = *(const s8v*)&Vt[(j * 16 + lo) * 48 + quad * 8];
            accO[j] = __builtin_amdgcn_mfma_f32_16x16x32_bf16(pf, bv, accO[j], 0, 0, 0);
        }
        __syncthreads();
        kk = kkn; vv = vvn;
    }

#pragma unroll
    for (int r = 0; r < 4; r++) {
        float l = l_r[r];
#pragma unroll
        for (int d = 1; d < 16; d <<= 1) l += __shfl_xor(l, d, 64);
        l_r[r] = 1.f / l;
    }
#pragma unroll
    for (int j = 0; j < 4; j++)
#pragma unroll
        for (int r = 0; r < 4; r++) {
            int qrow = q0 + quad * 4 + r;
            ctx[((size_t)b * NS + qrow) * 1024 + h * 64 + j * 16 + lo] = f2b(accO[j][r] * l_r[r]);
        }
}

// ---------------------------------------------------------------------------
// LayerNorm over last dim (1024). X bf16; g/b fp32 inputs; out bf16 or fp32.
__global__ __launch_bounds__(256) void ln_kernel(
    const unsigned short* __restrict__ X, const float* __restrict__ g,
    const float* __restrict__ bb, void* __restrict__ out, int outF32)
{
    const int row = blockIdx.x;
    const unsigned short* xr = X + (size_t)row * NE;
    s4v xv = *(const s4v*)(xr + threadIdx.x * 4);
    float v[4], s = 0.f, ss = 0.f;
#pragma unroll
    for (int i = 0; i < 4; i++) {
        v[i] = b2f((unsigned short)xv[i]);
        s += v[i]; ss += v[i] * v[i];
    }
#pragma unroll
    for (int d = 1; d < 64; d <<= 1) { s += __shfl_xor(s, d, 64); ss += __shfl_xor(ss, d, 64); }
    __shared__ float red[8];
    int wave = threadIdx.x >> 6, lane = threadIdx.x & 63;
    if (lane == 0) { red[wave] = s; red[4 + wave] = ss; }
    __syncthreads();
    s  = red[0] + red[1] + red[2] + red[3];
    ss = red[4] + red[5] + red[6] + red[7];
    float mu = s * (1.f / NE);
    float var = ss * (1.f / NE) - mu * mu;
    float rstd = rsqrtf(fmaxf(var, 0.f) + 1e-6f);
#pragma unroll
    for (int i = 0; i < 4; i++) {
        int c = threadIdx.x * 4 + i;
        size_t idx = (size_t)row * NE + c;
        float o = (v[i] - mu) * rstd * g[c] + bb[c];
        if (outF32) ((float*)out)[idx] = o;
        else        ((unsigned short*)out)[idx] = f2b(o);
    }
}

// ---------------------------------------------------------------------------
// Workspace map (peak 78 MB):
//   [0,8)   xb -> T1 -> T2
//   [8,16)  WTqkvg -> Cx -> X1
//   [16,18) WoT   [18,26) Wf1T   [26,34) WfgT   [34,42) Wf2T
//   [42,46) biasP (fp32, log2-domain, shift folded)
//   [46,78) QKVG -> H1
extern "C" void kernel_launch(void* const* d_in, const int* in_sizes, int n_in,
                              void* d_out, int out_size, void* d_ws, size_t ws_size,
                              hipStream_t stream)
{
    const float* x    = (const float*)d_in[0];
    const float* pe   = (const float*)d_in[1];
    const float* Wq   = (const float*)d_in[2];
    const float* bq   = (const float*)d_in[3];
    const float* Wk   = (const float*)d_in[4];
    const float* bk   = (const float*)d_in[5];
    const float* Wv   = (const float*)d_in[6];
    const float* bv   = (const float*)d_in[7];
    const float* Wo   = (const float*)d_in[8];
    const float* bo   = (const float*)d_in[9];
    const float* Wg   = (const float*)d_in[10];
    const float* bg   = (const float*)d_in[11];
    const float* Wf1  = (const float*)d_in[12];
    const float* bf1  = (const float*)d_in[13];
    const float* Wfg  = (const float*)d_in[14];
    const float* bfg  = (const float*)d_in[15];
    const float* Wf2  = (const float*)d_in[16];
    const float* bf2  = (const float*)d_in[17];
    const float* ln1g = (const float*)d_in[18];
    const float* ln1b = (const float*)d_in[19];
    const float* ln2g = (const float*)d_in[20];
    const float* ln2b = (const float*)d_in[21];

    char* ws = (char*)d_ws;
    unsigned short* xb    = (unsigned short*)ws;                         // [0,8)
    unsigned short* WTq   = (unsigned short*)(ws + ( 8ull << 20));       // [8,16)
    unsigned short* WoT   = (unsigned short*)(ws + (16ull << 20));       // [16,18)
    unsigned short* Wf1T  = (unsigned short*)(ws + (18ull << 20));       // [18,26)
    unsigned short* WfgT  = (unsigned short*)(ws + (26ull << 20));       // [26,34)
    unsigned short* Wf2T  = (unsigned short*)(ws + (34ull << 20));       // [34,42)
    float*          biasP = (float*)(ws + (42ull << 20));                // [42,46)
    unsigned short* QKVG  = (unsigned short*)(ws + (46ull << 20));       // [46,78)
    unsigned short* T1 = xb;
    unsigned short* Cx = WTq;
    unsigned short* X1 = WTq;
    unsigned short* H1 = QKVG;
    unsigned short* T2 = xb;

    dim3 blk(256);
    cvt_x_kernel<<<dim3(NM * NE / (256 * 8)), blk, 0, stream>>>(x, xb);
    cvt_t_kernel<<<dim3(16, 16, 5), blk, 0, stream>>>(
        Wq, Wk, Wv, Wg, Wo,
        WTq + 0ull * 1024 * 1024, WTq + 1ull * 1024 * 1024,
        WTq + 2ull * 1024 * 1024, WTq + 3ull * 1024 * 1024, WoT, NE, NE);
    cvt_t_kernel<<<dim3(64, 16, 2), blk, 0, stream>>>(
        Wf1, Wfg, nullptr, nullptr, nullptr,
        Wf1T, WfgT, nullptr, nullptr, nullptr, NE, NFF);
    cvt_t_kernel<<<dim3(16, 64, 1), blk, 0, stream>>>(
        Wf2, nullptr, nullptr, nullptr, nullptr,
        Wf2T, nullptr, nullptr, nullptr, nullptr, NFF, NE);
    posmean_kernel<<<dim3(NS * NS / 256), blk, 0, stream>>>(pe, biasP);

    // fused QKVG: [4096 x 4096] = xb @ [Wq|Wk|Wv|Wg], sigmoid on G segment
    gemm_bt<EPI_QKVG, 4><<<dim3(32, 32), blk, 0, stream>>>(
        xb, WTq, bq, bk, bv, bg, nullptr, nullptr, QKVG, NM, 4096, NE);

    attn_kernel<<<dim3(NS / 64, NB * NH), blk, 0, stream>>>(QKVG, biasP, Cx);

    // T1 = xb + G * (Cx@Wo + bo)   (T1 aliases xb: same-idx read-then-write)
    gemm_bt<EPI_GATE_RES, 2><<<dim3(8, 64), blk, 0, stream>>>(
        Cx, WoT, bo, nullptr, nullptr, nullptr, xb, QKVG + 3072, T1, NM, NE, NE);
    ln_kernel<<<dim3(NM), blk, 0, stream>>>(T1, ln1g, ln1b, X1, 0);

    // fused FF: H1 = (X1@Wf1 + bf1) * sigmoid(X1@Wfg + bfg)  [TM=2: occupancy]
    gemm_ff<2><<<dim3(32, 64), blk, 0, stream>>>(
        X1, Wf1T, WfgT, bf1, bfg, H1, NM, NFF, NE);

    gemm_bt<EPI_RES, 2><<<dim3(8, 64), blk, 0, stream>>>(
        H1, Wf2T, bf2, nullptr, nullptr, nullptr, X1, nullptr, T2, NM, NE, NFF);
    ln_kernel<<<dim3(NM), blk, 0, stream>>>(T2, ln2g, ln2b, d_out, 1);
}